// Round 1
// baseline (135.740 us; speedup 1.0000x reference)
//
#include <hip/hip_runtime.h>

#define NN 64
#define N3 (64*64*64)
#define DS 32
#define DS3 (32*32*32)

#define LOG2E 1.4426950408889634f

__device__ __forceinline__ float fexp2(float x) { return __builtin_amdgcn_exp2f(x); }

// per-axis linear-resize weights (matches jnp: i0=clip(floor(pos)), i1=clip(i0+1), w=pos-i0)
__device__ __forceinline__ void axw(int j, float scale, int nmax, int& i0, int& i1, float& w) {
    float pos = (float)j * scale;
    int f = (int)floorf(pos);
    if (f < 0) f = 0;
    if (f > nmax) f = nmax;
    i0 = f;
    i1 = (f + 1 <= nmax) ? f + 1 : nmax;
    w = pos - (float)f;
}

// ---------------- prior path ----------------

__global__ void k_downsample(const float* __restrict__ img, const float* __restrict__ atlas,
                             const float* __restrict__ alabel, const float* __restrict__ pnorm,
                             float2* __restrict__ f1, float2* __restrict__ f2, float4* __restrict__ alds)
{
    int idx = blockIdx.x * blockDim.x + threadIdx.x;
    if (idx >= DS3) return;
    int z = idx & 31, y = (idx >> 5) & 31, x = idx >> 10;

    const float scale = 63.0f / 31.0f;
    int x0,x1,y0,y1,z0,z1; float wx,wy,wz;
    axw(x, scale, 63, x0, x1, wx);
    axw(y, scale, 63, y0, y1, wy);
    axw(z, scale, 63, z0, z1, wz);

    float w000=(1-wx)*(1-wy)*(1-wz), w001=(1-wx)*(1-wy)*wz;
    float w010=(1-wx)*wy*(1-wz),     w011=(1-wx)*wy*wz;
    float w100=wx*(1-wy)*(1-wz),     w101=wx*(1-wy)*wz;
    float w110=wx*wy*(1-wz),         w111=wx*wy*wz;

    int c000=(x0*NN+y0)*NN+z0, c001=(x0*NN+y0)*NN+z1;
    int c010=(x0*NN+y1)*NN+z0, c011=(x0*NN+y1)*NN+z1;
    int c100=(x1*NN+y0)*NN+z0, c101=(x1*NN+y0)*NN+z1;
    int c110=(x1*NN+y1)*NN+z0, c111=(x1*NN+y1)*NN+z1;

    auto tri = [&](const float* p) -> float {
        return p[c000]*w000 + p[c001]*w001 + p[c010]*w010 + p[c011]*w011
             + p[c100]*w100 + p[c101]*w101 + p[c110]*w110 + p[c111]*w111;
    };
    float pn = pnorm[0];
    f1[idx] = make_float2(pn*tri(img),   pn*tri(img + N3));
    f2[idx] = make_float2(pn*tri(atlas), pn*tri(atlas + N3));

    // atlas_label is (x,y,z,c) channel-last
    auto tril = [&](int c) -> float {
        return alabel[c000*4+c]*w000 + alabel[c001*4+c]*w001 + alabel[c010*4+c]*w010 + alabel[c011*4+c]*w011
             + alabel[c100*4+c]*w100 + alabel[c101*4+c]*w101 + alabel[c110*4+c]*w110 + alabel[c111*4+c]*w111;
    };
    alds[idx] = make_float4(tril(0), tril(1), tril(2), tril(3));
}

__global__ void k_prior_msg(const float2* __restrict__ f1, const float2* __restrict__ f2,
                            const float4* __restrict__ alds, float4* __restrict__ pm)
{
    int idx = blockIdx.x * blockDim.x + threadIdx.x;
    if (idx >= DS3) return;
    int z = idx & 31, y = (idx >> 5) & 31, x = idx >> 10;

    float2 a = f1[idx];
    float a0=0.f, a1=0.f, a2=0.f, a3=0.f;
    for (int dx = -2; dx <= 2; ++dx) {
        int xx = x + dx; if ((unsigned)xx >= DS) continue;
        for (int dy = -2; dy <= 2; ++dy) {
            int yy = y + dy; if ((unsigned)yy >= DS) continue;
            for (int dz = -2; dz <= 2; ++dz) {
                int zz = z + dz; if ((unsigned)zz >= DS) continue;
                int j = (xx*DS + yy)*DS + zz;
                float2 b = f2[j];
                float d0 = a.x - b.x, d1 = a.y - b.y;
                float w = fexp2(-0.5f*LOG2E*(d0*d0 + d1*d1));
                float4 p = alds[j];
                a0 += p.x*w; a1 += p.y*w; a2 += p.z*w; a3 += p.w*w;
            }
        }
    }
    pm[idx] = make_float4(a0, a1, a2, a3);
}

__global__ void k_upsample_prior(const float4* __restrict__ pm, const float* __restrict__ pweight,
                                 const int* __restrict__ pstart, float4* __restrict__ prior4)
{
    int idx = blockIdx.x * blockDim.x + threadIdx.x;
    if (idx >= N3) return;
    int z = idx & 63, y = (idx >> 6) & 63, x = idx >> 12;

    const float scale = 31.0f / 63.0f;
    int x0,x1,y0,y1,z0,z1; float wx,wy,wz;
    axw(x, scale, 31, x0, x1, wx);
    axw(y, scale, 31, y0, y1, wy);
    axw(z, scale, 31, z0, z1, wz);

    float w000=(1-wx)*(1-wy)*(1-wz), w001=(1-wx)*(1-wy)*wz;
    float w010=(1-wx)*wy*(1-wz),     w011=(1-wx)*wy*wz;
    float w100=wx*(1-wy)*(1-wz),     w101=wx*(1-wy)*wz;
    float w110=wx*wy*(1-wz),         w111=wx*wy*wz;

    float4 p000=pm[(x0*DS+y0)*DS+z0], p001=pm[(x0*DS+y0)*DS+z1];
    float4 p010=pm[(x0*DS+y1)*DS+z0], p011=pm[(x0*DS+y1)*DS+z1];
    float4 p100=pm[(x1*DS+y0)*DS+z0], p101=pm[(x1*DS+y0)*DS+z1];
    float4 p110=pm[(x1*DS+y1)*DS+z0], p111=pm[(x1*DS+y1)*DS+z1];

    float4 r;
    r.x = w000*p000.x + w001*p001.x + w010*p010.x + w011*p011.x + w100*p100.x + w101*p101.x + w110*p110.x + w111*p111.x;
    r.y = w000*p000.y + w001*p001.y + w010*p010.y + w011*p011.y + w100*p100.y + w101*p101.y + w110*p110.y + w111*p111.y;
    r.z = w000*p000.z + w001*p001.z + w010*p010.z + w011*p011.z + w100*p100.z + w101*p101.z + w110*p110.z + w111*p111.z;
    r.w = w000*p000.w + w001*p001.w + w010*p010.w + w011*p011.w + w100*p100.w + w101*p101.w + w110*p110.w + w111*p111.w;

    float w = pweight[(pstart[0]+x)*96*96 + (pstart[1]+y)*96 + (pstart[2]+z)];
    r.x *= w; r.y *= w; r.z *= w; r.w *= w;
    prior4[idx] = r;
}

// ---------------- mean-field iteration ----------------

#define TB 8
#define TH 12   // tile + 2*SPAN halo
#define PZ 13   // z padded to break bank alignment

__global__ __launch_bounds__(512) void k_iter(
    const float* __restrict__ qin,
    const float* __restrict__ unary,
    const float* __restrict__ img,
    const float* __restrict__ snorm,
    const float* __restrict__ sweight,
    const float* __restrict__ compat,
    const float4* __restrict__ prior4,
    float* __restrict__ qout)
{
    __shared__ float4 pS[TH][TH][PZ];   // softmax(q), channel-interleaved
    __shared__ float2 iS[TH][TH][PZ];   // img*smooth_norm, 2ch interleaved

    const int tz = threadIdx.x, ty = threadIdx.y, tx = threadIdx.z;
    const int x0b = blockIdx.z * TB, y0b = blockIdx.y * TB, z0b = blockIdx.x * TB;
    const int tid = (tx*TB + ty)*TB + tz;
    const float sn = snorm[0];

    // halo load: q -> softmax -> pS; img*sn -> iS. OOB => p=0 (zero contribution).
    for (int i = tid; i < TH*TH*TH; i += TB*TB*TB) {
        int lz = i % TH; int r = i / TH;
        int ly = r % TH; int lx = r / TH;
        int gx = x0b + lx - 2, gy = y0b + ly - 2, gz = z0b + lz - 2;
        float4 p = make_float4(0.f, 0.f, 0.f, 0.f);
        float2 im = make_float2(0.f, 0.f);
        if ((unsigned)gx < NN && (unsigned)gy < NN && (unsigned)gz < NN) {
            int g = (gx*NN + gy)*NN + gz;
            float q0 = qin[g], q1 = qin[g+N3], q2 = qin[g+2*N3], q3 = qin[g+3*N3];
            float m = fmaxf(fmaxf(q0,q1), fmaxf(q2,q3));
            float e0 = fexp2((q0-m)*LOG2E);
            float e1 = fexp2((q1-m)*LOG2E);
            float e2 = fexp2((q2-m)*LOG2E);
            float e3 = fexp2((q3-m)*LOG2E);
            float inv = 1.0f/(e0+e1+e2+e3);
            p = make_float4(e0*inv, e1*inv, e2*inv, e3*inv);
            im = make_float2(img[g]*sn, img[g+N3]*sn);
        }
        pS[lx][ly][lz] = p;
        iS[lx][ly][lz] = im;
    }
    __syncthreads();

    const float2 mi = iS[tx+2][ty+2][tz+2];
    float a0=0.f, a1=0.f, a2=0.f, a3=0.f;
    for (int dx = 0; dx < 5; ++dx)
        for (int dy = 0; dy < 5; ++dy) {
            #pragma unroll
            for (int dz = 0; dz < 5; ++dz) {
                float2 nb = iS[tx+dx][ty+dy][tz+dz];
                float4 p  = pS[tx+dx][ty+dy][tz+dz];
                float d0 = nb.x - mi.x, d1 = nb.y - mi.y;
                float w = fexp2(-0.5f*LOG2E*(d0*d0 + d1*d1));
                a0 += p.x*w; a1 += p.y*w; a2 += p.z*w; a3 += p.w*w;
            }
        }

    const int g = ((x0b+tx)*NN + (y0b+ty))*NN + (z0b+tz);
    float4 pr = prior4[g];
    float pred0 = sweight[0]*a0 + pr.x;
    float pred1 = sweight[1]*a1 + pr.y;
    float pred2 = sweight[2]*a2 + pr.z;
    float pred3 = sweight[3]*a3 + pr.w;

    #pragma unroll
    for (int o = 0; o < 4; ++o) {
        float v = unary[o*N3 + g]
                + compat[o*4+0]*pred0 + compat[o*4+1]*pred1
                + compat[o*4+2]*pred2 + compat[o*4+3]*pred3;
        qout[o*N3 + g] = v;
    }
}

// ---------------- launcher ----------------

extern "C" void kernel_launch(void* const* d_in, const int* in_sizes, int n_in,
                              void* d_out, int out_size, void* d_ws, size_t ws_size,
                              hipStream_t stream)
{
    const float* unary   = (const float*)d_in[0];
    const float* img     = (const float*)d_in[1];
    const float* atlas   = (const float*)d_in[2];
    const float* alabel  = (const float*)d_in[3];
    const int*   pstart  = (const int*)d_in[4];
    const float* snorm   = (const float*)d_in[5];
    const float* sweight = (const float*)d_in[6];
    const float* pnorm   = (const float*)d_in[7];
    const float* pweight = (const float*)d_in[8];
    const float* compat  = (const float*)d_in[9];
    float* out = (float*)d_out;
    float* ws  = (float*)d_ws;

    float* prior4 = ws;              // 4*N3 floats (float4-interleaved per voxel)
    float* qtmp   = ws + 4*N3;       // 4*N3 floats (planar, like unary)
    float* f1     = ws + 8*N3;       // 2*DS3
    float* f2     = f1 + 2*DS3;      // 2*DS3
    float* alds   = f2 + 2*DS3;      // 4*DS3
    float* pm32   = alds + 4*DS3;    // 4*DS3

    k_downsample<<<DS3/256, 256, 0, stream>>>(img, atlas, alabel, pnorm,
                                              (float2*)f1, (float2*)f2, (float4*)alds);
    k_prior_msg<<<DS3/256, 256, 0, stream>>>((const float2*)f1, (const float2*)f2,
                                             (const float4*)alds, (float4*)pm32);
    k_upsample_prior<<<N3/256, 256, 0, stream>>>((const float4*)pm32, pweight, pstart,
                                                 (float4*)prior4);

    dim3 grid(NN/TB, NN/TB, NN/TB), block(TB, TB, TB);
    k_iter<<<grid, block, 0, stream>>>(unary, unary, img, snorm, sweight, compat, (const float4*)prior4, qtmp);
    k_iter<<<grid, block, 0, stream>>>(qtmp,  unary, img, snorm, sweight, compat, (const float4*)prior4, out);
    k_iter<<<grid, block, 0, stream>>>(out,   unary, img, snorm, sweight, compat, (const float4*)prior4, qtmp);
    k_iter<<<grid, block, 0, stream>>>(qtmp,  unary, img, snorm, sweight, compat, (const float4*)prior4, out);
}

// Round 2
// 114.753 us; speedup vs baseline: 1.1829x; 1.1829x over previous
//
#include <hip/hip_runtime.h>

#define NN 64
#define N3 (64*64*64)
#define DS 32
#define DS3 (32*32*32)

#define LOG2E 1.4426950408889634f
// sqrt(0.5 * log2(e)) — pre-scale so w = exp2(-(d0^2+d1^2))
#define FSCALE 0.8493218002880191f

__device__ __forceinline__ float fexp2(float x) { return __builtin_amdgcn_exp2f(x); }

__device__ __forceinline__ unsigned packbf2(float a, float b) {
    unsigned ua = __float_as_uint(a), ub = __float_as_uint(b);
    ua = (ua + 0x7fffu + ((ua >> 16) & 1u)) >> 16;          // bf16(a) in low half
    ub = (ub + 0x7fffu + ((ub >> 16) & 1u)) & 0xffff0000u;  // bf16(b) in high half
    return ua | ub;
}

__device__ __forceinline__ void axw(int j, float scale, int nmax, int& i0, int& i1, float& w) {
    float pos = (float)j * scale;
    int f = (int)floorf(pos);
    if (f < 0) f = 0;
    if (f > nmax) f = nmax;
    i0 = f;
    i1 = (f + 1 <= nmax) ? f + 1 : nmax;
    w = pos - (float)f;
}

// ---------------- prior path ----------------

__global__ void k_downsample(const float* __restrict__ img, const float* __restrict__ atlas,
                             const float* __restrict__ alabel, const float* __restrict__ pnorm,
                             float2* __restrict__ f1, float2* __restrict__ f2, float4* __restrict__ alds)
{
    int idx = blockIdx.x * blockDim.x + threadIdx.x;
    if (idx >= DS3) return;
    int z = idx & 31, y = (idx >> 5) & 31, x = idx >> 10;

    const float scale = 63.0f / 31.0f;
    int x0,x1,y0,y1,z0,z1; float wx,wy,wz;
    axw(x, scale, 63, x0, x1, wx);
    axw(y, scale, 63, y0, y1, wy);
    axw(z, scale, 63, z0, z1, wz);

    float w000=(1-wx)*(1-wy)*(1-wz), w001=(1-wx)*(1-wy)*wz;
    float w010=(1-wx)*wy*(1-wz),     w011=(1-wx)*wy*wz;
    float w100=wx*(1-wy)*(1-wz),     w101=wx*(1-wy)*wz;
    float w110=wx*wy*(1-wz),         w111=wx*wy*wz;

    int c000=(x0*NN+y0)*NN+z0, c001=(x0*NN+y0)*NN+z1;
    int c010=(x0*NN+y1)*NN+z0, c011=(x0*NN+y1)*NN+z1;
    int c100=(x1*NN+y0)*NN+z0, c101=(x1*NN+y0)*NN+z1;
    int c110=(x1*NN+y1)*NN+z0, c111=(x1*NN+y1)*NN+z1;

    auto tri = [&](const float* p) -> float {
        return p[c000]*w000 + p[c001]*w001 + p[c010]*w010 + p[c011]*w011
             + p[c100]*w100 + p[c101]*w101 + p[c110]*w110 + p[c111]*w111;
    };
    float pn = pnorm[0];
    f1[idx] = make_float2(pn*tri(img),   pn*tri(img + N3));
    f2[idx] = make_float2(pn*tri(atlas), pn*tri(atlas + N3));

    auto tril = [&](int c) -> float {
        return alabel[c000*4+c]*w000 + alabel[c001*4+c]*w001 + alabel[c010*4+c]*w010 + alabel[c011*4+c]*w011
             + alabel[c100*4+c]*w100 + alabel[c101*4+c]*w101 + alabel[c110*4+c]*w110 + alabel[c111*4+c]*w111;
    };
    alds[idx] = make_float4(tril(0), tril(1), tril(2), tril(3));
}

__global__ void k_prior_msg(const float2* __restrict__ f1, const float2* __restrict__ f2,
                            const float4* __restrict__ alds, float4* __restrict__ pm)
{
    int idx = blockIdx.x * blockDim.x + threadIdx.x;
    if (idx >= DS3) return;
    int z = idx & 31, y = (idx >> 5) & 31, x = idx >> 10;

    float2 a = f1[idx];
    float a0=0.f, a1=0.f, a2=0.f, a3=0.f;
    for (int dx = -2; dx <= 2; ++dx) {
        int xx = x + dx; if ((unsigned)xx >= DS) continue;
        for (int dy = -2; dy <= 2; ++dy) {
            int yy = y + dy; if ((unsigned)yy >= DS) continue;
            for (int dz = -2; dz <= 2; ++dz) {
                int zz = z + dz; if ((unsigned)zz >= DS) continue;
                int j = (xx*DS + yy)*DS + zz;
                float2 b = f2[j];
                float d0 = a.x - b.x, d1 = a.y - b.y;
                float w = fexp2(-0.5f*LOG2E*(d0*d0 + d1*d1));
                float4 p = alds[j];
                a0 += p.x*w; a1 += p.y*w; a2 += p.z*w; a3 += p.w*w;
            }
        }
    }
    pm[idx] = make_float4(a0, a1, a2, a3);
}

__global__ void k_upsample_prior(const float4* __restrict__ pm, const float* __restrict__ pweight,
                                 const int* __restrict__ pstart, float4* __restrict__ prior4)
{
    int idx = blockIdx.x * blockDim.x + threadIdx.x;
    if (idx >= N3) return;
    int z = idx & 63, y = (idx >> 6) & 63, x = idx >> 12;

    const float scale = 31.0f / 63.0f;
    int x0,x1,y0,y1,z0,z1; float wx,wy,wz;
    axw(x, scale, 31, x0, x1, wx);
    axw(y, scale, 31, y0, y1, wy);
    axw(z, scale, 31, z0, z1, wz);

    float w000=(1-wx)*(1-wy)*(1-wz), w001=(1-wx)*(1-wy)*wz;
    float w010=(1-wx)*wy*(1-wz),     w011=(1-wx)*wy*wz;
    float w100=wx*(1-wy)*(1-wz),     w101=wx*(1-wy)*wz;
    float w110=wx*wy*(1-wz),         w111=wx*wy*wz;

    float4 p000=pm[(x0*DS+y0)*DS+z0], p001=pm[(x0*DS+y0)*DS+z1];
    float4 p010=pm[(x0*DS+y1)*DS+z0], p011=pm[(x0*DS+y1)*DS+z1];
    float4 p100=pm[(x1*DS+y0)*DS+z0], p101=pm[(x1*DS+y0)*DS+z1];
    float4 p110=pm[(x1*DS+y1)*DS+z0], p111=pm[(x1*DS+y1)*DS+z1];

    float4 r;
    r.x = w000*p000.x + w001*p001.x + w010*p010.x + w011*p011.x + w100*p100.x + w101*p101.x + w110*p110.x + w111*p111.x;
    r.y = w000*p000.y + w001*p001.y + w010*p010.y + w011*p011.y + w100*p100.y + w101*p101.y + w110*p110.y + w111*p111.y;
    r.z = w000*p000.z + w001*p001.z + w010*p010.z + w011*p011.z + w100*p100.z + w101*p101.z + w110*p110.z + w111*p111.z;
    r.w = w000*p000.w + w001*p001.w + w010*p010.w + w011*p011.w + w100*p100.w + w101*p101.w + w110*p110.w + w111*p111.w;

    float w = pweight[(pstart[0]+x)*96*96 + (pstart[1]+y)*96 + (pstart[2]+z)];
    r.x *= w; r.y *= w; r.z *= w; r.w *= w;
    prior4[idx] = r;
}

// ---------------- mean-field iteration (z-register-blocked) ----------------

#define TXD 8
#define TYD 8
#define TZR 4          // thread groups along z
#define RZ 4           // z outputs per thread
#define TZD (TZR*RZ)   // 16
#define HX 12
#define HY 12
#define HZ 20          // z halo extent actually loaded
#define PZ 21          // padded z stride (bank spread)

__global__ __launch_bounds__(256) void k_iter(
    const float* __restrict__ qin,
    const float* __restrict__ unary,
    const float* __restrict__ img,
    const float* __restrict__ snorm,
    const float* __restrict__ sweight,
    const float* __restrict__ compat,
    const float4* __restrict__ prior4,
    float* __restrict__ qout)
{
    __shared__ float4    pS[HX][HY][PZ];   // softmax(q), f32x4
    __shared__ unsigned  iS[HX][HY][PZ];   // img * sn * FSCALE, bf16x2 packed

    const int tzg = threadIdx.x, ty = threadIdx.y, tx = threadIdx.z;
    const int x0b = blockIdx.z * TXD, y0b = blockIdx.y * TYD, z0b = blockIdx.x * TZD;
    const int tid = (tx*TYD + ty)*TZR + tzg;
    const float sc = snorm[0] * FSCALE;

    // ---- halo load: unrolled rounds so global loads batch-issue ----
    #pragma unroll
    for (int rr = 0; rr < 12; ++rr) {
        int i = tid + rr*256;
        if (i < HX*HY*HZ) {
            int lz = i % HZ; int r = i / HZ;
            int ly = r % HY; int lx = r / HY;
            int gx = x0b + lx - 2, gy = y0b + ly - 2, gz = z0b + lz - 2;
            float4 p = make_float4(0.f,0.f,0.f,0.f);
            unsigned fu = 0u;
            if ((unsigned)gx < NN && (unsigned)gy < NN && (unsigned)gz < NN) {
                int g = (gx*NN + gy)*NN + gz;
                float q0 = qin[g], q1 = qin[g+N3], q2 = qin[g+2*N3], q3 = qin[g+3*N3];
                float m = fmaxf(fmaxf(q0,q1), fmaxf(q2,q3));
                float e0 = fexp2((q0-m)*LOG2E);
                float e1 = fexp2((q1-m)*LOG2E);
                float e2 = fexp2((q2-m)*LOG2E);
                float e3 = fexp2((q3-m)*LOG2E);
                float inv = 1.0f/(e0+e1+e2+e3);
                p = make_float4(e0*inv, e1*inv, e2*inv, e3*inv);
                fu = packbf2(img[g]*sc, img[g+N3]*sc);
            }
            pS[lx][ly][lz] = p;
            iS[lx][ly][lz] = fu;
        }
    }

    // hoisted epilogue operands (hide global latency under the main loop)
    const int tz0 = tzg * RZ;
    const int g = ((x0b+tx)*NN + (y0b+ty))*NN + z0b + tz0;
    float4 pr0 = prior4[g+0], pr1 = prior4[g+1], pr2 = prior4[g+2], pr3 = prior4[g+3];
    float4 un0 = *(const float4*)(unary + 0*N3 + g);
    float4 un1 = *(const float4*)(unary + 1*N3 + g);
    float4 un2 = *(const float4*)(unary + 2*N3 + g);
    float4 un3 = *(const float4*)(unary + 3*N3 + g);
    float sw0 = sweight[0], sw1 = sweight[1], sw2 = sweight[2], sw3 = sweight[3];
    float cw[16];
    #pragma unroll
    for (int k = 0; k < 16; ++k) cw[k] = compat[k];

    __syncthreads();

    // center features (from LDS so the d=0 term is exactly w=1)
    float2 cf[RZ];
    #pragma unroll
    for (int r = 0; r < RZ; ++r) {
        unsigned u = iS[tx+2][ty+2][tz0+2+r];
        cf[r] = make_float2(__uint_as_float(u << 16), __uint_as_float(u & 0xffff0000u));
    }

    float4 acc[RZ];
    #pragma unroll
    for (int r = 0; r < RZ; ++r) acc[r] = make_float4(0.f,0.f,0.f,0.f);

    for (int dx = 0; dx < 5; ++dx) {
        for (int dy = 0; dy < 5; ++dy) {
            const float4*   pp = &pS[tx+dx][ty+dy][tz0];
            const unsigned* fp = &iS[tx+dx][ty+dy][tz0];
            float4 p[8]; unsigned fu[8];
            #pragma unroll
            for (int k = 0; k < 8; ++k) { p[k] = pp[k]; fu[k] = fp[k]; }
            float2 nf[8];
            #pragma unroll
            for (int k = 0; k < 8; ++k)
                nf[k] = make_float2(__uint_as_float(fu[k] << 16), __uint_as_float(fu[k] & 0xffff0000u));
            #pragma unroll
            for (int r = 0; r < RZ; ++r) {
                #pragma unroll
                for (int dz = 0; dz < 5; ++dz) {
                    int k = r + dz;
                    float d0 = nf[k].x - cf[r].x;
                    float d1 = nf[k].y - cf[r].y;
                    float t = __builtin_fmaf(d1, d1, d0*d0);
                    float w = fexp2(-t);
                    acc[r].x += w*p[k].x;
                    acc[r].y += w*p[k].y;
                    acc[r].z += w*p[k].z;
                    acc[r].w += w*p[k].w;
                }
            }
        }
    }

    // epilogue: pred = sw*msg + prior; q = unary + compat @ pred
    float4 vo0, vo1, vo2, vo3;
    {
        float p0, p1, p2, p3;
        p0 = sw0*acc[0].x + pr0.x; p1 = sw1*acc[0].y + pr0.y; p2 = sw2*acc[0].z + pr0.z; p3 = sw3*acc[0].w + pr0.w;
        vo0.x = un0.x + cw[0]*p0 + cw[1]*p1 + cw[2]*p2 + cw[3]*p3;
        vo1.x = un1.x + cw[4]*p0 + cw[5]*p1 + cw[6]*p2 + cw[7]*p3;
        vo2.x = un2.x + cw[8]*p0 + cw[9]*p1 + cw[10]*p2 + cw[11]*p3;
        vo3.x = un3.x + cw[12]*p0 + cw[13]*p1 + cw[14]*p2 + cw[15]*p3;
        p0 = sw0*acc[1].x + pr1.x; p1 = sw1*acc[1].y + pr1.y; p2 = sw2*acc[1].z + pr1.z; p3 = sw3*acc[1].w + pr1.w;
        vo0.y = un0.y + cw[0]*p0 + cw[1]*p1 + cw[2]*p2 + cw[3]*p3;
        vo1.y = un1.y + cw[4]*p0 + cw[5]*p1 + cw[6]*p2 + cw[7]*p3;
        vo2.y = un2.y + cw[8]*p0 + cw[9]*p1 + cw[10]*p2 + cw[11]*p3;
        vo3.y = un3.y + cw[12]*p0 + cw[13]*p1 + cw[14]*p2 + cw[15]*p3;
        p0 = sw0*acc[2].x + pr2.x; p1 = sw1*acc[2].y + pr2.y; p2 = sw2*acc[2].z + pr2.z; p3 = sw3*acc[2].w + pr2.w;
        vo0.z = un0.z + cw[0]*p0 + cw[1]*p1 + cw[2]*p2 + cw[3]*p3;
        vo1.z = un1.z + cw[4]*p0 + cw[5]*p1 + cw[6]*p2 + cw[7]*p3;
        vo2.z = un2.z + cw[8]*p0 + cw[9]*p1 + cw[10]*p2 + cw[11]*p3;
        vo3.z = un3.z + cw[12]*p0 + cw[13]*p1 + cw[14]*p2 + cw[15]*p3;
        p0 = sw0*acc[3].x + pr3.x; p1 = sw1*acc[3].y + pr3.y; p2 = sw2*acc[3].z + pr3.z; p3 = sw3*acc[3].w + pr3.w;
        vo0.w = un0.w + cw[0]*p0 + cw[1]*p1 + cw[2]*p2 + cw[3]*p3;
        vo1.w = un1.w + cw[4]*p0 + cw[5]*p1 + cw[6]*p2 + cw[7]*p3;
        vo2.w = un2.w + cw[8]*p0 + cw[9]*p1 + cw[10]*p2 + cw[11]*p3;
        vo3.w = un3.w + cw[12]*p0 + cw[13]*p1 + cw[14]*p2 + cw[15]*p3;
    }
    *(float4*)(qout + 0*N3 + g) = vo0;
    *(float4*)(qout + 1*N3 + g) = vo1;
    *(float4*)(qout + 2*N3 + g) = vo2;
    *(float4*)(qout + 3*N3 + g) = vo3;
}

// ---------------- launcher ----------------

extern "C" void kernel_launch(void* const* d_in, const int* in_sizes, int n_in,
                              void* d_out, int out_size, void* d_ws, size_t ws_size,
                              hipStream_t stream)
{
    const float* unary   = (const float*)d_in[0];
    const float* img     = (const float*)d_in[1];
    const float* atlas   = (const float*)d_in[2];
    const float* alabel  = (const float*)d_in[3];
    const int*   pstart  = (const int*)d_in[4];
    const float* snorm   = (const float*)d_in[5];
    const float* sweight = (const float*)d_in[6];
    const float* pnorm   = (const float*)d_in[7];
    const float* pweight = (const float*)d_in[8];
    const float* compat  = (const float*)d_in[9];
    float* out = (float*)d_out;
    float* ws  = (float*)d_ws;

    float* prior4 = ws;              // 4*N3
    float* qtmp   = ws + 4*N3;       // 4*N3
    float* f1     = ws + 8*N3;       // 2*DS3
    float* f2     = f1 + 2*DS3;      // 2*DS3
    float* alds   = f2 + 2*DS3;      // 4*DS3
    float* pm32   = alds + 4*DS3;    // 4*DS3

    k_downsample<<<DS3/256, 256, 0, stream>>>(img, atlas, alabel, pnorm,
                                              (float2*)f1, (float2*)f2, (float4*)alds);
    k_prior_msg<<<DS3/256, 256, 0, stream>>>((const float2*)f1, (const float2*)f2,
                                             (const float4*)alds, (float4*)pm32);
    k_upsample_prior<<<N3/256, 256, 0, stream>>>((const float4*)pm32, pweight, pstart,
                                                 (float4*)prior4);

    dim3 grid(NN/TZD, NN/TYD, NN/TXD), block(TZR, TYD, TXD);
    k_iter<<<grid, block, 0, stream>>>(unary, unary, img, snorm, sweight, compat, (const float4*)prior4, qtmp);
    k_iter<<<grid, block, 0, stream>>>(qtmp,  unary, img, snorm, sweight, compat, (const float4*)prior4, out);
    k_iter<<<grid, block, 0, stream>>>(out,   unary, img, snorm, sweight, compat, (const float4*)prior4, qtmp);
    k_iter<<<grid, block, 0, stream>>>(qtmp,  unary, img, snorm, sweight, compat, (const float4*)prior4, out);
}

// Round 4
// 102.716 us; speedup vs baseline: 1.3215x; 1.1172x over previous
//
#include <hip/hip_runtime.h>

#define NN 64
#define N3 (64*64*64)
#define DS 32
#define DS3 (32*32*32)

#define LOG2E 1.4426950408889634f
// sqrt(0.5 * log2(e)) — features pre-scaled so w = exp2(-dot2(d,d))
#define FSCALE 0.8493218002880191f

typedef _Float16 h2  __attribute__((ext_vector_type(2)));
typedef __fp16   h2f __attribute__((ext_vector_type(2)));

__device__ __forceinline__ float fexp2(float x) { return __builtin_amdgcn_exp2f(x); }

__device__ __forceinline__ h2 u2h(unsigned u) { union { unsigned u; h2 h; } c; c.u = u; return c.h; }
__device__ __forceinline__ unsigned h2u(h2 h) { union { unsigned u; h2 h; } c; c.h = h; return c.u; }
__device__ __forceinline__ h2 pkh(float a, float b) {
    union { h2f a; h2 b; } c; c.a = __builtin_amdgcn_cvt_pkrtz(a, b); return c.b;
}
__device__ __forceinline__ float fdot2(h2 a, h2 b) {
    union { h2 h; h2f f; } ca, cb; ca.h = a; cb.h = b;
    return __builtin_amdgcn_fdot2(ca.f, cb.f, 0.0f, false);
}

__device__ __forceinline__ void axw(int j, float scale, int nmax, int& i0, int& i1, float& w) {
    float pos = (float)j * scale;
    int f = (int)floorf(pos);
    if (f < 0) f = 0;
    if (f > nmax) f = nmax;
    i0 = f;
    i1 = (f + 1 <= nmax) ? f + 1 : nmax;
    w = pos - (float)f;
}

// ---------------- prior path ----------------

// outputs: f1pk[DS3] = packed f16x2 of f1*pn*FSCALE
//          nb[DS3]   = { f2 packed, label01 packed, label23 packed, 0 }
__global__ __launch_bounds__(128) void k_downsample(
    const float* __restrict__ img, const float* __restrict__ atlas,
    const float* __restrict__ alabel, const float* __restrict__ pnorm,
    unsigned* __restrict__ f1pk, uint4* __restrict__ nb)
{
    int idx = blockIdx.x * 128 + threadIdx.x;   // grid covers DS3 exactly
    int z = idx & 31, y = (idx >> 5) & 31, x = idx >> 10;

    const float scale = 63.0f / 31.0f;
    int x0,x1,y0,y1,z0,z1; float wx,wy,wz;
    axw(x, scale, 63, x0, x1, wx);
    axw(y, scale, 63, y0, y1, wy);
    axw(z, scale, 63, z0, z1, wz);

    float w000=(1-wx)*(1-wy)*(1-wz), w001=(1-wx)*(1-wy)*wz;
    float w010=(1-wx)*wy*(1-wz),     w011=(1-wx)*wy*wz;
    float w100=wx*(1-wy)*(1-wz),     w101=wx*(1-wy)*wz;
    float w110=wx*wy*(1-wz),         w111=wx*wy*wz;

    int c000=(x0*NN+y0)*NN+z0, c001=(x0*NN+y0)*NN+z1;
    int c010=(x0*NN+y1)*NN+z0, c011=(x0*NN+y1)*NN+z1;
    int c100=(x1*NN+y0)*NN+z0, c101=(x1*NN+y0)*NN+z1;
    int c110=(x1*NN+y1)*NN+z0, c111=(x1*NN+y1)*NN+z1;

    auto tri = [&](const float* p) -> float {
        return p[c000]*w000 + p[c001]*w001 + p[c010]*w010 + p[c011]*w011
             + p[c100]*w100 + p[c101]*w101 + p[c110]*w110 + p[c111]*w111;
    };
    float pnf = pnorm[0] * FSCALE;
    f1pk[idx] = h2u(pkh(pnf*tri(img), pnf*tri(img + N3)));

    auto tril = [&](int c) -> float {
        return alabel[c000*4+c]*w000 + alabel[c001*4+c]*w001 + alabel[c010*4+c]*w010 + alabel[c011*4+c]*w011
             + alabel[c100*4+c]*w100 + alabel[c101*4+c]*w101 + alabel[c110*4+c]*w110 + alabel[c111*4+c]*w111;
    };
    nb[idx] = make_uint4(h2u(pkh(pnf*tri(atlas), pnf*tri(atlas + N3))),
                         h2u(pkh(tril(0), tril(1))),
                         h2u(pkh(tril(2), tril(3))), 0u);
}

__global__ __launch_bounds__(128) void k_prior_msg(
    const unsigned* __restrict__ f1pk, const uint4* __restrict__ nb,
    float4* __restrict__ pm)
{
    int idx = blockIdx.x * 128 + threadIdx.x;
    int z = idx & 31, y = (idx >> 5) & 31, x = idx >> 10;

    h2 ncf = -u2h(f1pk[idx]);
    float a0=0.f, a1=0.f, a2=0.f, a3=0.f;
    for (int dx = -2; dx <= 2; ++dx) {
        int xx = x + dx; if ((unsigned)xx >= DS) continue;
        for (int dy = -2; dy <= 2; ++dy) {
            int yy = y + dy; if ((unsigned)yy >= DS) continue;
            int base = (xx*DS + yy)*DS;
            #pragma unroll
            for (int dz = -2; dz <= 2; ++dz) {
                int zz = z + dz; if ((unsigned)zz >= DS) continue;
                uint4 v = nb[base + zz];
                h2 d = u2h(v.x) + ncf;
                float t = fdot2(d, d);
                float w = fexp2(-t);
                h2 l01 = u2h(v.y), l23 = u2h(v.z);
                a0 += w*(float)l01.x; a1 += w*(float)l01.y;
                a2 += w*(float)l23.x; a3 += w*(float)l23.y;
            }
        }
    }
    pm[idx] = make_float4(a0, a1, a2, a3);
}

__global__ void k_upsample_prior(const float4* __restrict__ pm, const float* __restrict__ pweight,
                                 const int* __restrict__ pstart, float4* __restrict__ prior4)
{
    int idx = blockIdx.x * blockDim.x + threadIdx.x;
    if (idx >= N3) return;
    int z = idx & 63, y = (idx >> 6) & 63, x = idx >> 12;

    const float scale = 31.0f / 63.0f;
    int x0,x1,y0,y1,z0,z1; float wx,wy,wz;
    axw(x, scale, 31, x0, x1, wx);
    axw(y, scale, 31, y0, y1, wy);
    axw(z, scale, 31, z0, z1, wz);

    float w000=(1-wx)*(1-wy)*(1-wz), w001=(1-wx)*(1-wy)*wz;
    float w010=(1-wx)*wy*(1-wz),     w011=(1-wx)*wy*wz;
    float w100=wx*(1-wy)*(1-wz),     w101=wx*(1-wy)*wz;
    float w110=wx*wy*(1-wz),         w111=wx*wy*wz;

    float4 p000=pm[(x0*DS+y0)*DS+z0], p001=pm[(x0*DS+y0)*DS+z1];
    float4 p010=pm[(x0*DS+y1)*DS+z0], p011=pm[(x0*DS+y1)*DS+z1];
    float4 p100=pm[(x1*DS+y0)*DS+z0], p101=pm[(x1*DS+y0)*DS+z1];
    float4 p110=pm[(x1*DS+y1)*DS+z0], p111=pm[(x1*DS+y1)*DS+z1];

    float4 r;
    r.x = w000*p000.x + w001*p001.x + w010*p010.x + w011*p011.x + w100*p100.x + w101*p101.x + w110*p110.x + w111*p111.x;
    r.y = w000*p000.y + w001*p001.y + w010*p010.y + w011*p011.y + w100*p100.y + w101*p101.y + w110*p110.y + w111*p111.y;
    r.z = w000*p000.z + w001*p001.z + w010*p010.z + w011*p011.z + w100*p100.z + w101*p101.z + w110*p110.z + w111*p111.z;
    r.w = w000*p000.w + w001*p001.w + w010*p010.w + w011*p011.w + w100*p100.w + w101*p101.w + w110*p110.w + w111*p111.w;

    float w = pweight[(pstart[0]+x)*96*96 + (pstart[1]+y)*96 + (pstart[2]+z)];
    r.x *= w; r.y *= w; r.z *= w; r.w *= w;
    prior4[idx] = r;
}

// ---------------- mean-field iteration ----------------
// tile 8x8x16, RZ=2 outputs/thread along z, 512 threads, grid 256 = 1 block/CU,
// 8 waves/CU = 2 waves/SIMD.

#define TXD 8
#define TYD 8
#define TZR 8
#define RZ 2
#define TZD (TZR*RZ)   // 16
#define HX 12
#define HY 12
#define HZ 20          // z halo extent loaded
#define PZ 22          // padded z stride (even -> 16B-aligned pair reads)

__global__ __launch_bounds__(512, 2) void k_iter(
    const float* __restrict__ qin,
    const float* __restrict__ unary,
    const float* __restrict__ img,
    const float* __restrict__ snorm,
    const float* __restrict__ sweight,
    const float* __restrict__ compat,
    const float4* __restrict__ prior4,
    float* __restrict__ qout)
{
    __shared__ __align__(16) uint2    pS[HX][HY][PZ];  // softmax(q) packed f16x4
    __shared__ __align__(8)  unsigned fS[HX][HY][PZ];  // img*sn*FSCALE packed f16x2

    const int tzg = threadIdx.x, ty = threadIdx.y, tx = threadIdx.z;
    const int x0b = blockIdx.z * TXD, y0b = blockIdx.y * TYD, z0b = blockIdx.x * TZD;
    const int tid = (tx*TYD + ty)*TZR + tzg;
    const float sc = snorm[0] * FSCALE;

    // ---- halo load: 12x12x20 = 2880 voxels, 6 rounds of 512 ----
    #pragma unroll
    for (int rr = 0; rr < 6; ++rr) {
        int i = tid + rr*512;
        if (i < HX*HY*HZ) {
            int lz = i % HZ; int r = i / HZ;
            int ly = r % HY; int lx = r / HY;
            int gx = x0b + lx - 2, gy = y0b + ly - 2, gz = z0b + lz - 2;
            uint2 pu = make_uint2(0u, 0u);
            unsigned fu = 0u;
            if ((unsigned)gx < NN && (unsigned)gy < NN && (unsigned)gz < NN) {
                int g = (gx*NN + gy)*NN + gz;
                float q0 = qin[g], q1 = qin[g+N3], q2 = qin[g+2*N3], q3 = qin[g+3*N3];
                float m = fmaxf(fmaxf(q0,q1), fmaxf(q2,q3));
                float e0 = fexp2((q0-m)*LOG2E);
                float e1 = fexp2((q1-m)*LOG2E);
                float e2 = fexp2((q2-m)*LOG2E);
                float e3 = fexp2((q3-m)*LOG2E);
                float inv = 1.0f/(e0+e1+e2+e3);
                pu = make_uint2(h2u(pkh(e0*inv, e1*inv)), h2u(pkh(e2*inv, e3*inv)));
                fu = h2u(pkh(img[g]*sc, img[g+N3]*sc));
            }
            pS[lx][ly][lz] = pu;
            fS[lx][ly][lz] = fu;
        }
    }

    // hoisted epilogue operands
    const int tz0 = tzg * RZ;
    const int g = ((x0b+tx)*NN + (y0b+ty))*NN + z0b + tz0;
    float4 pr0 = prior4[g], pr1 = prior4[g+1];
    float2 un0 = *(const float2*)(unary + 0*N3 + g);
    float2 un1 = *(const float2*)(unary + 1*N3 + g);
    float2 un2 = *(const float2*)(unary + 2*N3 + g);
    float2 un3 = *(const float2*)(unary + 3*N3 + g);
    float sw0 = sweight[0], sw1 = sweight[1], sw2 = sweight[2], sw3 = sweight[3];
    float cw[16];
    #pragma unroll
    for (int k = 0; k < 16; ++k) cw[k] = compat[k];

    __syncthreads();

    // negated center features (read from LDS so d=0 term gives exactly w=1)
    h2 ncf0 = -u2h(fS[tx+2][ty+2][tz0+2]);
    h2 ncf1 = -u2h(fS[tx+2][ty+2][tz0+3]);

    float4 acc0 = make_float4(0.f,0.f,0.f,0.f);
    float4 acc1 = make_float4(0.f,0.f,0.f,0.f);

    for (int dx = 0; dx < 5; ++dx) {
        #pragma unroll
        for (int dy = 0; dy < 5; ++dy) {
            const uint4* pp = reinterpret_cast<const uint4*>(&pS[tx+dx][ty+dy][tz0]);
            const uint2* fp = reinterpret_cast<const uint2*>(&fS[tx+dx][ty+dy][tz0]);
            uint4 qa = pp[0], qb = pp[1], qc = pp[2];     // 6 voxels of packed p
            uint2 fa = fp[0], fb = fp[1], fc = fp[2];     // 6 voxels of packed f

            unsigned fz[6]  = { fa.x, fa.y, fb.x, fb.y, fc.x, fc.y };
            unsigned p01[6] = { qa.x, qa.z, qb.x, qb.z, qc.x, qc.z };
            unsigned p23[6] = { qa.y, qa.w, qb.y, qb.w, qc.y, qc.w };

            #pragma unroll
            for (int dz = 0; dz < 5; ++dz) {
                // r = 0
                {
                    h2 d = u2h(fz[dz]) + ncf0;
                    float t = fdot2(d, d);
                    float w = fexp2(-t);
                    h2 a = u2h(p01[dz]), b = u2h(p23[dz]);
                    acc0.x += w*(float)a.x; acc0.y += w*(float)a.y;
                    acc0.z += w*(float)b.x; acc0.w += w*(float)b.y;
                }
                // r = 1
                {
                    h2 d = u2h(fz[dz+1]) + ncf1;
                    float t = fdot2(d, d);
                    float w = fexp2(-t);
                    h2 a = u2h(p01[dz+1]), b = u2h(p23[dz+1]);
                    acc1.x += w*(float)a.x; acc1.y += w*(float)a.y;
                    acc1.z += w*(float)b.x; acc1.w += w*(float)b.y;
                }
            }
        }
    }

    // epilogue: pred = sw*msg + prior; q = unary + compat @ pred
    float p0, p1, p2, p3;
    float r00, r10, r20, r30, r01, r11, r21, r31;
    p0 = sw0*acc0.x + pr0.x; p1 = sw1*acc0.y + pr0.y; p2 = sw2*acc0.z + pr0.z; p3 = sw3*acc0.w + pr0.w;
    r00 = un0.x + cw[0]*p0  + cw[1]*p1  + cw[2]*p2  + cw[3]*p3;
    r10 = un1.x + cw[4]*p0  + cw[5]*p1  + cw[6]*p2  + cw[7]*p3;
    r20 = un2.x + cw[8]*p0  + cw[9]*p1  + cw[10]*p2 + cw[11]*p3;
    r30 = un3.x + cw[12]*p0 + cw[13]*p1 + cw[14]*p2 + cw[15]*p3;
    p0 = sw0*acc1.x + pr1.x; p1 = sw1*acc1.y + pr1.y; p2 = sw2*acc1.z + pr1.z; p3 = sw3*acc1.w + pr1.w;
    r01 = un0.y + cw[0]*p0  + cw[1]*p1  + cw[2]*p2  + cw[3]*p3;
    r11 = un1.y + cw[4]*p0  + cw[5]*p1  + cw[6]*p2  + cw[7]*p3;
    r21 = un2.y + cw[8]*p0  + cw[9]*p1  + cw[10]*p2 + cw[11]*p3;
    r31 = un3.y + cw[12]*p0 + cw[13]*p1 + cw[14]*p2 + cw[15]*p3;

    *(float2*)(qout + 0*N3 + g) = make_float2(r00, r01);
    *(float2*)(qout + 1*N3 + g) = make_float2(r10, r11);
    *(float2*)(qout + 2*N3 + g) = make_float2(r20, r21);
    *(float2*)(qout + 3*N3 + g) = make_float2(r30, r31);
}

// ---------------- launcher ----------------

extern "C" void kernel_launch(void* const* d_in, const int* in_sizes, int n_in,
                              void* d_out, int out_size, void* d_ws, size_t ws_size,
                              hipStream_t stream)
{
    const float* unary   = (const float*)d_in[0];
    const float* img     = (const float*)d_in[1];
    const float* atlas   = (const float*)d_in[2];
    const float* alabel  = (const float*)d_in[3];
    const int*   pstart  = (const int*)d_in[4];
    const float* snorm   = (const float*)d_in[5];
    const float* sweight = (const float*)d_in[6];
    const float* pnorm   = (const float*)d_in[7];
    const float* pweight = (const float*)d_in[8];
    const float* compat  = (const float*)d_in[9];
    float* out = (float*)d_out;
    float* ws  = (float*)d_ws;

    float*    prior4 = ws;                          // 4*N3 floats
    float*    qtmp   = ws + 4*N3;                   // 4*N3 floats
    unsigned* f1pk   = (unsigned*)(ws + 8*N3);      // DS3 uints
    uint4*    nbuf   = (uint4*)(f1pk + DS3);        // DS3 uint4
    float*    pm32   = (float*)(nbuf + DS3);        // 4*DS3 floats

    k_downsample<<<DS3/128, 128, 0, stream>>>(img, atlas, alabel, pnorm, f1pk, nbuf);
    k_prior_msg<<<DS3/128, 128, 0, stream>>>(f1pk, nbuf, (float4*)pm32);
    k_upsample_prior<<<N3/256, 256, 0, stream>>>((const float4*)pm32, pweight, pstart,
                                                 (float4*)prior4);

    dim3 grid(NN/TZD, NN/TYD, NN/TXD), block(TZR, TYD, TXD);
    k_iter<<<grid, block, 0, stream>>>(unary, unary, img, snorm, sweight, compat, (const float4*)prior4, qtmp);
    k_iter<<<grid, block, 0, stream>>>(qtmp,  unary, img, snorm, sweight, compat, (const float4*)prior4, out);
    k_iter<<<grid, block, 0, stream>>>(out,   unary, img, snorm, sweight, compat, (const float4*)prior4, qtmp);
    k_iter<<<grid, block, 0, stream>>>(qtmp,  unary, img, snorm, sweight, compat, (const float4*)prior4, out);
}

// Round 5
// 95.583 us; speedup vs baseline: 1.4201x; 1.0746x over previous
//
#include <hip/hip_runtime.h>

#define NN 64
#define N3 (64*64*64)
#define DS 32
#define DS3 (32*32*32)

#define LOG2E 1.4426950408889634f
// sqrt(0.5 * log2(e)) — features pre-scaled so w = exp2(-dot2(d,d))
#define FSCALE 0.8493218002880191f

typedef _Float16 h2  __attribute__((ext_vector_type(2)));
typedef __fp16   h2f __attribute__((ext_vector_type(2)));

__device__ __forceinline__ float fexp2(float x) { return __builtin_amdgcn_exp2f(x); }

__device__ __forceinline__ h2 u2h(unsigned u) { union { unsigned u; h2 h; } c; c.u = u; return c.h; }
__device__ __forceinline__ unsigned h2u(h2 h) { union { unsigned u; h2 h; } c; c.h = h; return c.u; }
__device__ __forceinline__ h2 pkh(float a, float b) {
    union { h2f a; h2 b; } c; c.a = __builtin_amdgcn_cvt_pkrtz(a, b); return c.b;
}
__device__ __forceinline__ float fdot2(h2 a, h2 b) {
    union { h2 h; h2f f; } ca, cb; ca.h = a; cb.h = b;
    return __builtin_amdgcn_fdot2(ca.f, cb.f, 0.0f, false);
}

__device__ __forceinline__ void axw(int j, float scale, int nmax, int& i0, int& i1, float& w) {
    float pos = (float)j * scale;
    int f = (int)floorf(pos);
    if (f < 0) f = 0;
    if (f > nmax) f = nmax;
    i0 = f;
    i1 = (f + 1 <= nmax) ? f + 1 : nmax;
    w = pos - (float)f;
}

// ---------------- prior path ----------------

// outputs: f1pk[DS3] = packed f16x2 of f1*pn*FSCALE
//          nb[DS3]   = { f2 packed, label01 packed, label23 packed, 0 }
__global__ __launch_bounds__(128) void k_downsample(
    const float* __restrict__ img, const float* __restrict__ atlas,
    const float* __restrict__ alabel, const float* __restrict__ pnorm,
    unsigned* __restrict__ f1pk, uint4* __restrict__ nb)
{
    int idx = blockIdx.x * 128 + threadIdx.x;   // grid covers DS3 exactly
    int z = idx & 31, y = (idx >> 5) & 31, x = idx >> 10;

    const float scale = 63.0f / 31.0f;
    int x0,x1,y0,y1,z0,z1; float wx,wy,wz;
    axw(x, scale, 63, x0, x1, wx);
    axw(y, scale, 63, y0, y1, wy);
    axw(z, scale, 63, z0, z1, wz);

    float w000=(1-wx)*(1-wy)*(1-wz), w001=(1-wx)*(1-wy)*wz;
    float w010=(1-wx)*wy*(1-wz),     w011=(1-wx)*wy*wz;
    float w100=wx*(1-wy)*(1-wz),     w101=wx*(1-wy)*wz;
    float w110=wx*wy*(1-wz),         w111=wx*wy*wz;

    int c000=(x0*NN+y0)*NN+z0, c001=(x0*NN+y0)*NN+z1;
    int c010=(x0*NN+y1)*NN+z0, c011=(x0*NN+y1)*NN+z1;
    int c100=(x1*NN+y0)*NN+z0, c101=(x1*NN+y0)*NN+z1;
    int c110=(x1*NN+y1)*NN+z0, c111=(x1*NN+y1)*NN+z1;

    auto tri = [&](const float* p) -> float {
        return p[c000]*w000 + p[c001]*w001 + p[c010]*w010 + p[c011]*w011
             + p[c100]*w100 + p[c101]*w101 + p[c110]*w110 + p[c111]*w111;
    };
    float pnf = pnorm[0] * FSCALE;
    f1pk[idx] = h2u(pkh(pnf*tri(img), pnf*tri(img + N3)));

    auto tril = [&](int c) -> float {
        return alabel[c000*4+c]*w000 + alabel[c001*4+c]*w001 + alabel[c010*4+c]*w010 + alabel[c011*4+c]*w011
             + alabel[c100*4+c]*w100 + alabel[c101*4+c]*w101 + alabel[c110*4+c]*w110 + alabel[c111*4+c]*w111;
    };
    nb[idx] = make_uint4(h2u(pkh(pnf*tri(atlas), pnf*tri(atlas + N3))),
                         h2u(pkh(tril(0), tril(1))),
                         h2u(pkh(tril(2), tril(3))), 0u);
}

__global__ __launch_bounds__(128) void k_prior_msg(
    const unsigned* __restrict__ f1pk, const uint4* __restrict__ nb,
    float4* __restrict__ pm)
{
    int idx = blockIdx.x * 128 + threadIdx.x;
    int z = idx & 31, y = (idx >> 5) & 31, x = idx >> 10;

    h2 ncf = -u2h(f1pk[idx]);
    float a0=0.f, a1=0.f, a2=0.f, a3=0.f;
    for (int dx = -2; dx <= 2; ++dx) {
        int xx = x + dx; if ((unsigned)xx >= DS) continue;
        for (int dy = -2; dy <= 2; ++dy) {
            int yy = y + dy; if ((unsigned)yy >= DS) continue;
            int base = (xx*DS + yy)*DS;
            #pragma unroll
            for (int dz = -2; dz <= 2; ++dz) {
                int zz = z + dz; if ((unsigned)zz >= DS) continue;
                uint4 v = nb[base + zz];
                h2 d = u2h(v.x) + ncf;
                float t = fdot2(d, d);
                float w = fexp2(-t);
                h2 l01 = u2h(v.y), l23 = u2h(v.z);
                a0 += w*(float)l01.x; a1 += w*(float)l01.y;
                a2 += w*(float)l23.x; a3 += w*(float)l23.y;
            }
        }
    }
    pm[idx] = make_float4(a0, a1, a2, a3);
}

// ---------------- mean-field iteration ----------------
// tile 8x8x16 (1024 voxels), 1024 threads: each voxel is handled by TWO
// threads (wave-uniform split s over the 25 (dx,dy) phases), each thread
// covers RZ=2 consecutive z voxels. 16 waves/block, grid 256 = 1 block/CU
// -> 16 waves/CU = 4 waves/SIMD. Prior upsample fused into the epilogue.

#define TXD 8
#define TYD 8
#define TZR 8
#define RZ 2
#define TZD (TZR*RZ)   // 16
#define HX 12
#define HY 12
#define HZ 20          // z halo extent loaded
#define PZ 22          // padded z stride (even -> 16B-aligned pair reads)

template<bool QV_IN, bool QV_OUT>
__global__ __launch_bounds__(1024, 4) void k_iter(
    const float* __restrict__ qin,      // QV_IN ? float4-interleaved : planar [4][N3]
    const float* __restrict__ unary,
    const float* __restrict__ img,
    const float* __restrict__ snorm,
    const float* __restrict__ sweight,
    const float* __restrict__ compat,
    const float4* __restrict__ pm,      // 32^3 prior message
    const float* __restrict__ pweight,
    const int* __restrict__ pstart,
    float* __restrict__ qout)           // QV_OUT ? float4-interleaved : planar
{
    __shared__ __align__(16) uint2    pS[HX][HY][PZ];  // softmax(q) packed f16x4
    __shared__ __align__(8)  unsigned fS[HX][HY][PZ];  // img*sn*FSCALE packed f16x2
    __shared__ __align__(16) float4   accS[TXD*TYD*TZR][2];

    const int tzg = threadIdx.x, ty = threadIdx.y;
    const int tx = threadIdx.z & 7, s = threadIdx.z >> 3;   // s is wave-uniform
    const int x0b = blockIdx.z * TXD, y0b = blockIdx.y * TYD, z0b = blockIdx.x * TZD;
    const int tid = threadIdx.x + TZR*threadIdx.y + TZR*TYD*threadIdx.z;
    const float sc = snorm[0] * FSCALE;

    // ---- halo load: 12x12x20 = 2880 voxels, 3 rounds of 1024 ----
    #pragma unroll
    for (int rr = 0; rr < 3; ++rr) {
        int i = tid + rr*1024;
        if (i < HX*HY*HZ) {
            int lz = i % HZ; int r = i / HZ;
            int ly = r % HY; int lx = r / HY;
            int gx = x0b + lx - 2, gy = y0b + ly - 2, gz = z0b + lz - 2;
            uint2 pu = make_uint2(0u, 0u);
            unsigned fu = 0u;
            if ((unsigned)gx < NN && (unsigned)gy < NN && (unsigned)gz < NN) {
                int g = (gx*NN + gy)*NN + gz;
                float q0, q1, q2, q3;
                if (QV_IN) {
                    float4 qv = reinterpret_cast<const float4*>(qin)[g];
                    q0 = qv.x; q1 = qv.y; q2 = qv.z; q3 = qv.w;
                } else {
                    q0 = qin[g]; q1 = qin[g+N3]; q2 = qin[g+2*N3]; q3 = qin[g+3*N3];
                }
                float m = fmaxf(fmaxf(q0,q1), fmaxf(q2,q3));
                float e0 = fexp2((q0-m)*LOG2E);
                float e1 = fexp2((q1-m)*LOG2E);
                float e2 = fexp2((q2-m)*LOG2E);
                float e3 = fexp2((q3-m)*LOG2E);
                float inv = 1.0f/(e0+e1+e2+e3);
                pu = make_uint2(h2u(pkh(e0*inv, e1*inv)), h2u(pkh(e2*inv, e3*inv)));
                fu = h2u(pkh(img[g]*sc, img[g+N3]*sc));
            }
            pS[lx][ly][lz] = pu;
            fS[lx][ly][lz] = fu;
        }
    }

    const int tz0 = tzg * RZ;
    const int gx = x0b + tx, gy = y0b + ty, gz = z0b + tz0;

    // ---- prior term (s==1 waves only; epilogue owner). pm is L1/L2-hot. ----
    float4 pr0 = make_float4(0.f,0.f,0.f,0.f), pr1 = make_float4(0.f,0.f,0.f,0.f);
    if (s == 1) {
        const float S13 = 31.0f / 63.0f;
        float posx = (float)gx * S13; int xc0 = (int)posx; float wxf = posx - (float)xc0;
        int xc1 = xc0 < 31 ? xc0+1 : 31;
        float posy = (float)gy * S13; int yc0 = (int)posy; float wyf = posy - (float)yc0;
        int yc1 = yc0 < 31 ? yc0+1 : 31;
        int r00i = (xc0*DS+yc0)*DS, r01i = (xc0*DS+yc1)*DS;
        int r10i = (xc1*DS+yc0)*DS, r11i = (xc1*DS+yc1)*DS;
        auto upz = [&](int gzv) -> float4 {
            float posz = (float)gzv * S13; int zc0 = (int)posz; float wzf = posz - (float)zc0;
            int zc1 = zc0 < 31 ? zc0+1 : 31;
            float4 p000 = pm[r00i+zc0], p001 = pm[r00i+zc1];
            float4 p010 = pm[r01i+zc0], p011 = pm[r01i+zc1];
            float4 p100 = pm[r10i+zc0], p101 = pm[r10i+zc1];
            float4 p110 = pm[r11i+zc0], p111 = pm[r11i+zc1];
            float w000=(1-wxf)*(1-wyf)*(1-wzf), w001=(1-wxf)*(1-wyf)*wzf;
            float w010=(1-wxf)*wyf*(1-wzf),     w011=(1-wxf)*wyf*wzf;
            float w100=wxf*(1-wyf)*(1-wzf),     w101=wxf*(1-wyf)*wzf;
            float w110=wxf*wyf*(1-wzf),         w111=wxf*wyf*wzf;
            float4 r;
            r.x = w000*p000.x + w001*p001.x + w010*p010.x + w011*p011.x + w100*p100.x + w101*p101.x + w110*p110.x + w111*p111.x;
            r.y = w000*p000.y + w001*p001.y + w010*p010.y + w011*p011.y + w100*p100.y + w101*p101.y + w110*p110.y + w111*p111.y;
            r.z = w000*p000.z + w001*p001.z + w010*p010.z + w011*p011.z + w100*p100.z + w101*p101.z + w110*p110.z + w111*p111.z;
            r.w = w000*p000.w + w001*p001.w + w010*p010.w + w011*p011.w + w100*p100.w + w101*p101.w + w110*p110.w + w111*p111.w;
            return r;
        };
        pr0 = upz(gz);
        pr1 = upz(gz+1);
        int ps0 = pstart[0], ps1 = pstart[1], ps2 = pstart[2];
        int pwbase = (ps0+gx)*96*96 + (ps1+gy)*96 + ps2 + gz;
        float pwa = pweight[pwbase], pwb = pweight[pwbase+1];
        pr0.x *= pwa; pr0.y *= pwa; pr0.z *= pwa; pr0.w *= pwa;
        pr1.x *= pwb; pr1.y *= pwb; pr1.z *= pwb; pr1.w *= pwb;
    }

    __syncthreads();

    // negated center features (read from LDS so d=0 term gives exactly w=1)
    h2 ncf0 = -u2h(fS[tx+2][ty+2][tz0+2]);
    h2 ncf1 = -u2h(fS[tx+2][ty+2][tz0+3]);

    float4 acc0 = make_float4(0.f,0.f,0.f,0.f);
    float4 acc1 = make_float4(0.f,0.f,0.f,0.f);

    // wave-uniform split of the 25 (dx,dy) phases: s=0 -> 13 phases, s=1 -> 12
    for (int p = s; p < 25; p += 2) {
        int dx = p / 5, dy = p - dx*5;
        const uint4* pp = reinterpret_cast<const uint4*>(&pS[tx+dx][ty+dy][tz0]);
        const uint2* fp = reinterpret_cast<const uint2*>(&fS[tx+dx][ty+dy][tz0]);
        uint4 qa = pp[0], qb = pp[1], qc = pp[2];     // 6 voxels of packed p
        uint2 fa = fp[0], fb = fp[1], fc = fp[2];     // 6 voxels of packed f

        unsigned fz[6]  = { fa.x, fa.y, fb.x, fb.y, fc.x, fc.y };
        unsigned p01[6] = { qa.x, qa.z, qb.x, qb.z, qc.x, qc.z };
        unsigned p23[6] = { qa.y, qa.w, qb.y, qb.w, qc.y, qc.w };

        #pragma unroll
        for (int dz = 0; dz < 5; ++dz) {
            {
                h2 d = u2h(fz[dz]) + ncf0;
                float t = fdot2(d, d);
                float w = fexp2(-t);
                h2 a = u2h(p01[dz]), b = u2h(p23[dz]);
                acc0.x += w*(float)a.x; acc0.y += w*(float)a.y;
                acc0.z += w*(float)b.x; acc0.w += w*(float)b.y;
            }
            {
                h2 d = u2h(fz[dz+1]) + ncf1;
                float t = fdot2(d, d);
                float w = fexp2(-t);
                h2 a = u2h(p01[dz+1]), b = u2h(p23[dz+1]);
                acc1.x += w*(float)a.x; acc1.y += w*(float)a.y;
                acc1.z += w*(float)b.x; acc1.w += w*(float)b.y;
            }
        }
    }

    const int pid = (tx*TYD + ty)*TZR + tzg;
    if (s == 0) {
        accS[pid][0] = acc0;
        accS[pid][1] = acc1;
    }
    __syncthreads();

    if (s == 1) {
        float4 o0 = accS[pid][0], o1 = accS[pid][1];
        acc0.x += o0.x; acc0.y += o0.y; acc0.z += o0.z; acc0.w += o0.w;
        acc1.x += o1.x; acc1.y += o1.y; acc1.z += o1.z; acc1.w += o1.w;

        const int g = (gx*NN + gy)*NN + gz;
        float2 un0 = *(const float2*)(unary + 0*N3 + g);
        float2 un1 = *(const float2*)(unary + 1*N3 + g);
        float2 un2 = *(const float2*)(unary + 2*N3 + g);
        float2 un3 = *(const float2*)(unary + 3*N3 + g);
        float sw0 = sweight[0], sw1 = sweight[1], sw2 = sweight[2], sw3 = sweight[3];
        float cw[16];
        #pragma unroll
        for (int k = 0; k < 16; ++k) cw[k] = compat[k];

        float p0, p1, p2, p3;
        float r00, r10, r20, r30, r01, r11, r21, r31;
        p0 = sw0*acc0.x + pr0.x; p1 = sw1*acc0.y + pr0.y; p2 = sw2*acc0.z + pr0.z; p3 = sw3*acc0.w + pr0.w;
        r00 = un0.x + cw[0]*p0  + cw[1]*p1  + cw[2]*p2  + cw[3]*p3;
        r10 = un1.x + cw[4]*p0  + cw[5]*p1  + cw[6]*p2  + cw[7]*p3;
        r20 = un2.x + cw[8]*p0  + cw[9]*p1  + cw[10]*p2 + cw[11]*p3;
        r30 = un3.x + cw[12]*p0 + cw[13]*p1 + cw[14]*p2 + cw[15]*p3;
        p0 = sw0*acc1.x + pr1.x; p1 = sw1*acc1.y + pr1.y; p2 = sw2*acc1.z + pr1.z; p3 = sw3*acc1.w + pr1.w;
        r01 = un0.y + cw[0]*p0  + cw[1]*p1  + cw[2]*p2  + cw[3]*p3;
        r11 = un1.y + cw[4]*p0  + cw[5]*p1  + cw[6]*p2  + cw[7]*p3;
        r21 = un2.y + cw[8]*p0  + cw[9]*p1  + cw[10]*p2 + cw[11]*p3;
        r31 = un3.y + cw[12]*p0 + cw[13]*p1 + cw[14]*p2 + cw[15]*p3;

        if (QV_OUT) {
            reinterpret_cast<float4*>(qout)[g]   = make_float4(r00, r10, r20, r30);
            reinterpret_cast<float4*>(qout)[g+1] = make_float4(r01, r11, r21, r31);
        } else {
            *(float2*)(qout + 0*N3 + g) = make_float2(r00, r01);
            *(float2*)(qout + 1*N3 + g) = make_float2(r10, r11);
            *(float2*)(qout + 2*N3 + g) = make_float2(r20, r21);
            *(float2*)(qout + 3*N3 + g) = make_float2(r30, r31);
        }
    }
}

// ---------------- launcher ----------------

extern "C" void kernel_launch(void* const* d_in, const int* in_sizes, int n_in,
                              void* d_out, int out_size, void* d_ws, size_t ws_size,
                              hipStream_t stream)
{
    const float* unary   = (const float*)d_in[0];
    const float* img     = (const float*)d_in[1];
    const float* atlas   = (const float*)d_in[2];
    const float* alabel  = (const float*)d_in[3];
    const int*   pstart  = (const int*)d_in[4];
    const float* snorm   = (const float*)d_in[5];
    const float* sweight = (const float*)d_in[6];
    const float* pnorm   = (const float*)d_in[7];
    const float* pweight = (const float*)d_in[8];
    const float* compat  = (const float*)d_in[9];
    float* out = (float*)d_out;
    float* ws  = (float*)d_ws;

    float*    qA   = ws;                            // float4-interleaved q, 4*N3 floats
    float*    qB   = ws + 4*N3;                     // float4-interleaved q, 4*N3 floats
    unsigned* f1pk = (unsigned*)(ws + 8*N3);        // DS3 uints
    uint4*    nbuf = (uint4*)(f1pk + DS3);          // DS3 uint4
    float4*   pm   = (float4*)(nbuf + DS3);         // DS3 float4

    k_downsample<<<DS3/128, 128, 0, stream>>>(img, atlas, alabel, pnorm, f1pk, nbuf);
    k_prior_msg<<<DS3/128, 128, 0, stream>>>(f1pk, nbuf, pm);

    dim3 grid(NN/TZD, NN/TYD, NN/TXD), block(TZR, TYD, 16);
    k_iter<false,true><<<grid, block, 0, stream>>>(unary, unary, img, snorm, sweight, compat, pm, pweight, pstart, qA);
    k_iter<true, true><<<grid, block, 0, stream>>>(qA,    unary, img, snorm, sweight, compat, pm, pweight, pstart, qB);
    k_iter<true, true><<<grid, block, 0, stream>>>(qB,    unary, img, snorm, sweight, compat, pm, pweight, pstart, qA);
    k_iter<true,false><<<grid, block, 0, stream>>>(qA,    unary, img, snorm, sweight, compat, pm, pweight, pstart, out);
}